// Round 5
// baseline (567.764 us; speedup 1.0000x reference)
//
#include <hip/hip_runtime.h>
#include <hip/hip_bf16.h>
#include <hip/hip_fp16.h>
#include <cstdint>
#include <cstddef>

#define NN 100000
#define EE 1600000
#define GG 2048
#define STRIDE 72   // padded CSR stride; max degree ~ 1+Poisson(16) << 72

constexpr int NB_EDGE = (EE + NN + 255) / 256;  // 6641 edge blocks
constexpr int NB_GEMM = NN / 16;                // 6250 gemm blocks
constexpr int NB_OUT  = (GG + 255) / 256;       // 8 out-init blocks

__device__ __forceinline__ float lrelu(float v) { return v > 0.f ? v : 0.2f * v; }

// ---------------- shared GEMM body (layer GEMM + attention-logit epilogue) --
// One wave = 4 rows; x-row pointers wave-uniform (SGPR via readfirstlane).
template <int FIN>
__device__ __forceinline__ void gemm_body(int bidx, const float* __restrict__ X,
                                          const float* __restrict__ W,
                                          const float* __restrict__ asrc,
                                          const float* __restrict__ adst,
                                          float* __restrict__ H,
                                          float* __restrict__ als,
                                          float* __restrict__ ald) {
    int j  = threadIdx.x & 63;
    int ty = threadIdx.x >> 6;
    int row = __builtin_amdgcn_readfirstlane(bidx * 16 + ty * 4);
    const float* x0 = X + (size_t)row * FIN;
    const float* x1 = x0 + FIN;
    const float* x2 = x1 + FIN;
    const float* x3 = x2 + FIN;
    float a0 = 0.f, a1 = 0.f, a2 = 0.f, a3 = 0.f;
#pragma unroll
    for (int k = 0; k < FIN; k += 4) {
        float4 xa = *(const float4*)(x0 + k);
        float4 xb = *(const float4*)(x1 + k);
        float4 xc = *(const float4*)(x2 + k);
        float4 xd = *(const float4*)(x3 + k);
        float w0 = W[(k + 0) * 64 + j];
        float w1 = W[(k + 1) * 64 + j];
        float w2 = W[(k + 2) * 64 + j];
        float w3 = W[(k + 3) * 64 + j];
        a0 += xa.x * w0 + xa.y * w1 + xa.z * w2 + xa.w * w3;
        a1 += xb.x * w0 + xb.y * w1 + xb.z * w2 + xb.w * w3;
        a2 += xc.x * w0 + xc.y * w1 + xc.z * w2 + xc.w * w3;
        a3 += xd.x * w0 + xd.y * w1 + xd.z * w2 + xd.w * w3;
    }
    H[(size_t)(row + 0) * 64 + j] = a0;
    H[(size_t)(row + 1) * 64 + j] = a1;
    H[(size_t)(row + 2) * 64 + j] = a2;
    H[(size_t)(row + 3) * 64 + j] = a3;
    float asj = asrc[j], adj = adst[j];
    float accs[4] = {a0, a1, a2, a3};
#pragma unroll
    for (int r = 0; r < 4; r++) {
        float vs = accs[r] * asj;
        float vd = accs[r] * adj;
#pragma unroll
        for (int off = 8; off > 0; off >>= 1) {
            vs += __shfl_xor(vs, off, 64);
            vd += __shfl_xor(vd, off, 64);
        }
        if ((j & 15) == 0) {
            int h = j >> 4;
            als[(size_t)(row + r) * 4 + h] = vs;
            ald[(size_t)(row + r) * 4 + h] = vd;
        }
    }
}

// ---------------- single-pass padded CSR build || layer-0 GEMM || out init --
// Padded CSR: only per-dst contiguity matters (no-max softmax is order-
// invariant), so count+placement collapse into ONE atomic pass:
//   r = atomicAdd(&deg[d],1); col[d*STRIDE+r] = s
// This deletes the alloc scan and the scatter kernel (1.7M random reads of
// offs/rank + an ei re-read). Overflow (deg > STRIDE, probabilistically
// absent: max 1+Poisson(16) over 100K nodes ~ 45) goes to a correct side list.
__global__ __launch_bounds__(256) void k_build(const int* __restrict__ ei,
                                               int* __restrict__ deg,
                                               int* __restrict__ col,
                                               int* __restrict__ ofc,
                                               int* __restrict__ ofl,
                                               const float* __restrict__ X,
                                               const float* __restrict__ W,
                                               const float* __restrict__ asrc,
                                               const float* __restrict__ adst,
                                               float* __restrict__ H,
                                               float* __restrict__ als,
                                               float* __restrict__ ald,
                                               const float* __restrict__ head_b,
                                               float* __restrict__ out) {
    int b = blockIdx.x;
    if (b < NB_EDGE) {
        int i = b * 256 + threadIdx.x;
        if (i < EE + NN) {
            int s, d;
            if (i < EE) { s = ei[i]; d = ei[EE + i]; } else { s = d = i - EE; }
            int r = atomicAdd(&deg[d], 1);
            if (r < STRIDE) col[d * STRIDE + r] = s;
            else { int o = atomicAdd(ofc, 1); ofl[2 * o] = s; ofl[2 * o + 1] = d; }
        }
    } else if (b < NB_EDGE + NB_GEMM) {
        gemm_body<128>(b - NB_EDGE, X, W, asrc, adst, H, als, ald);
    } else {
        int gI = (b - NB_EDGE - NB_GEMM) * 256 + threadIdx.x;
        if (gI < GG) out[gI] = head_b[0];
    }
}

// ---------------- fused aggregate(L) + GEMM(L+1) ----------------------------
// Round-2/4 gather structure verbatim (8 edges in flight, no-max softmax,
// fused next-layer GEMM from LDS); only the segment base changed to n*STRIDE.
__global__ __launch_bounds__(256) void k_aggf(
    const float* __restrict__ H, const float* __restrict__ als,
    const float* __restrict__ ald,
    const int* __restrict__ deg, const int* __restrict__ col,
    const int* __restrict__ ofc, const int* __restrict__ ofl,
    const float* __restrict__ bias,          // layer L bias (on aggregated out)
    const float* __restrict__ W,             // layer L+1 weights [64][64]
    const float* __restrict__ asrc,          // layer L+1 a_src [4][16]
    const float* __restrict__ adst,          // layer L+1 a_dst [4][16]
    float* __restrict__ Hn, float* __restrict__ alsn, float* __restrict__ aldn) {
    __shared__ float wl[4096];       // W staged: 16 KB
    __shared__ float xs[16 * 68];    // 16 rows, stride 68 (bank-conflict pad)
    int tid = threadIdx.x;
    int g = tid >> 4;          // group (node) 0..15
    int l = tid & 15;          // lane in group = float4-chunk index 0..15
    int n = blockIdx.x * 16 + g;   // NN % 16 == 0 -> always valid
    int start = n * STRIDE;
    int len = deg[n];
    int hsel = l >> 2;         // head of this lane's channel quad
    float adh = ald[(size_t)n * 4 + hsel];
    const float4* Hp = (const float4*)H + l;

    // stage W while the gather waits on memory
#pragma unroll
    for (int t = 0; t < 4; t++)
        ((float4*)wl)[tid + t * 256] = ((const float4*)W)[tid + t * 256];

    float4 acc = {0.f, 0.f, 0.f, 0.f};
    float ssum = 0.f;
    int len_in = len <= STRIDE ? len : STRIDE;
    for (int e = 0; e < len_in; e += 8) {
        bool  v[8];
        int   s[8];
#pragma unroll
        for (int i = 0; i < 8; i++) {
            v[i] = (e + i < len_in);
            s[i] = v[i] ? col[start + e + i] : 0;
        }
        float  w[8];
        float4 hr[8];
#pragma unroll
        for (int i = 0; i < 8; i++) {
            float a = als[(size_t)s[i] * 4 + hsel];
            hr[i] = Hp[(size_t)s[i] * 16];
            float ev = lrelu(a + adh);
            w[i] = v[i] ? __expf(ev) : 0.f;
        }
#pragma unroll
        for (int i = 0; i < 8; i++) {
            ssum  += w[i];
            acc.x = fmaf(w[i], hr[i].x, acc.x);
            acc.y = fmaf(w[i], hr[i].y, acc.y);
            acc.z = fmaf(w[i], hr[i].z, acc.z);
            acc.w = fmaf(w[i], hr[i].w, acc.w);
        }
    }
    if (len > STRIDE) {      // correctness-only path; empty in practice
        int oc = *ofc;
        for (int k2 = 0; k2 < oc; k2++) {
            if (ofl[2 * k2 + 1] == n) {
                int s0 = ofl[2 * k2];
                float a = als[(size_t)s0 * 4 + hsel];
                float4 h0 = Hp[(size_t)s0 * 16];
                float w0 = __expf(lrelu(a + adh));
                ssum += w0;
                acc.x = fmaf(w0, h0.x, acc.x); acc.y = fmaf(w0, h0.y, acc.y);
                acc.z = fmaf(w0, h0.z, acc.z); acc.w = fmaf(w0, h0.w, acc.w);
            }
        }
    }
    float inv = 1.f / (ssum + 1e-16f);
    float4 b4 = ((const float4*)bias)[l];
    float* xr = xs + g * 68 + 4 * l;
    xr[0] = fmaxf(acc.x * inv + b4.x, 0.f);
    xr[1] = fmaxf(acc.y * inv + b4.y, 0.f);
    xr[2] = fmaxf(acc.z * inv + b4.z, 0.f);
    xr[3] = fmaxf(acc.w * inv + b4.w, 0.f);

    __syncthreads();   // xs + wl ready

    // ---- GEMM: thread (g,l) -> row n, output channels 4l..4l+3 ------------
    float4 o = {0.f, 0.f, 0.f, 0.f};
    const float* xrow = xs + g * 68;
    const float* wcol = wl + 4 * l;
#pragma unroll
    for (int k = 0; k < 64; k += 4) {
        float4 xv = *(const float4*)(xrow + k);
        float4 w0 = *(const float4*)(wcol + (k + 0) * 64);
        float4 w1 = *(const float4*)(wcol + (k + 1) * 64);
        float4 w2 = *(const float4*)(wcol + (k + 2) * 64);
        float4 w3 = *(const float4*)(wcol + (k + 3) * 64);
        o.x += xv.x * w0.x + xv.y * w1.x + xv.z * w2.x + xv.w * w3.x;
        o.y += xv.x * w0.y + xv.y * w1.y + xv.z * w2.y + xv.w * w3.y;
        o.z += xv.x * w0.z + xv.y * w1.z + xv.z * w2.z + xv.w * w3.z;
        o.w += xv.x * w0.w + xv.y * w1.w + xv.z * w2.w + xv.w * w3.w;
    }
    ((float4*)Hn)[(size_t)n * 16 + l] = o;

    // attention logits for layer L+1: channels 4l..4l+3 are all in head l>>2
    float4 av = ((const float4*)asrc)[l];
    float4 dv = ((const float4*)adst)[l];
    float vs = o.x * av.x + o.y * av.y + o.z * av.z + o.w * av.w;
    float vd = o.x * dv.x + o.y * dv.y + o.z * dv.z + o.w * dv.w;
    vs += __shfl_xor(vs, 1, 16); vs += __shfl_xor(vs, 2, 16);
    vd += __shfl_xor(vd, 1, 16); vd += __shfl_xor(vd, 2, 16);
    if ((l & 3) == 0) {
        int h = l >> 2;
        alsn[(size_t)n * 4 + h] = vs;
        aldn[(size_t)n * 4 + h] = vd;
    }
}

// ---------------- last layer: aggregate + head projection + pool ------------
__global__ __launch_bounds__(256) void k_aggl(
    const float* __restrict__ H, const float* __restrict__ als,
    const float* __restrict__ ald,
    const int* __restrict__ deg, const int* __restrict__ col,
    const int* __restrict__ ofc, const int* __restrict__ ofl,
    const float* __restrict__ bias, const int* __restrict__ batch,
    const float* __restrict__ hw, float* __restrict__ out) {
    int tid = threadIdx.x;
    int g = tid >> 4;
    int l = tid & 15;
    int n = blockIdx.x * 16 + g;
    int start = n * STRIDE;
    int len = deg[n];
    int hsel = l >> 2;
    float adh = ald[(size_t)n * 4 + hsel];
    const float4* Hp = (const float4*)H + l;

    float4 acc = {0.f, 0.f, 0.f, 0.f};
    float ssum = 0.f;
    int len_in = len <= STRIDE ? len : STRIDE;
    for (int e = 0; e < len_in; e += 8) {
        bool  v[8];
        int   s[8];
#pragma unroll
        for (int i = 0; i < 8; i++) {
            v[i] = (e + i < len_in);
            s[i] = v[i] ? col[start + e + i] : 0;
        }
        float  w[8];
        float4 hr[8];
#pragma unroll
        for (int i = 0; i < 8; i++) {
            float a = als[(size_t)s[i] * 4 + hsel];
            hr[i] = Hp[(size_t)s[i] * 16];
            float ev = lrelu(a + adh);
            w[i] = v[i] ? __expf(ev) : 0.f;
        }
#pragma unroll
        for (int i = 0; i < 8; i++) {
            ssum  += w[i];
            acc.x = fmaf(w[i], hr[i].x, acc.x);
            acc.y = fmaf(w[i], hr[i].y, acc.y);
            acc.z = fmaf(w[i], hr[i].z, acc.z);
            acc.w = fmaf(w[i], hr[i].w, acc.w);
        }
    }
    if (len > STRIDE) {      // correctness-only path; empty in practice
        int oc = *ofc;
        for (int k2 = 0; k2 < oc; k2++) {
            if (ofl[2 * k2 + 1] == n) {
                int s0 = ofl[2 * k2];
                float a = als[(size_t)s0 * 4 + hsel];
                float4 h0 = Hp[(size_t)s0 * 16];
                float w0 = __expf(lrelu(a + adh));
                ssum += w0;
                acc.x = fmaf(w0, h0.x, acc.x); acc.y = fmaf(w0, h0.y, acc.y);
                acc.z = fmaf(w0, h0.z, acc.z); acc.w = fmaf(w0, h0.w, acc.w);
            }
        }
    }
    float inv = 1.f / (ssum + 1e-16f);
    float4 b4 = ((const float4*)bias)[l];
    float4 w4 = ((const float4*)hw)[l];
    float t = fmaxf(acc.x * inv + b4.x, 0.f) * w4.x
            + fmaxf(acc.y * inv + b4.y, 0.f) * w4.y
            + fmaxf(acc.z * inv + b4.z, 0.f) * w4.z
            + fmaxf(acc.w * inv + b4.w, 0.f) * w4.w;
#pragma unroll
    for (int off = 8; off > 0; off >>= 1) t += __shfl_xor(t, off, 16);
    if (l == 0) atomicAdd(&out[batch[n]], t);
}

// ---------------- launch -----------------------------------------------------
extern "C" void kernel_launch(void* const* d_in, const int* in_sizes, int n_in,
                              void* d_out, int out_size, void* d_ws, size_t ws_size,
                              hipStream_t stream) {
    const float* x     = (const float*)d_in[0];
    const int*   ei    = (const int*)d_in[1];
    const int*   batch = (const int*)d_in[2];
    const float* Wm[3] = {(const float*)d_in[3], (const float*)d_in[7],  (const float*)d_in[11]};
    const float* As[3] = {(const float*)d_in[4], (const float*)d_in[8],  (const float*)d_in[12]};
    const float* Ad[3] = {(const float*)d_in[5], (const float*)d_in[9],  (const float*)d_in[13]};
    const float* Bb[3] = {(const float*)d_in[6], (const float*)d_in[10], (const float*)d_in[14]};
    const float* hw = (const float*)d_in[15];
    const float* hb = (const float*)d_in[16];
    float* out = (float*)d_out;

    uint8_t* w = (uint8_t*)d_ws;
    auto alloc = [&](size_t bytes) -> void* {
        void* p = (void*)w;
        w += (bytes + 255) & ~(size_t)255;
        return p;
    };
    float* H    = (float*)alloc((size_t)NN * 64 * 4);       // ping (gather source)
    float* Bf   = (float*)alloc((size_t)NN * 64 * 4);       // pong
    float* als  = (float*)alloc((size_t)NN * 4 * 4);
    float* ald  = (float*)alloc((size_t)NN * 4 * 4);
    float* als2 = (float*)alloc((size_t)NN * 4 * 4);
    float* ald2 = (float*)alloc((size_t)NN * 4 * 4);
    int*   deg  = (int*)alloc((size_t)(NN + 64) * 4);       // + ofc word
    int*   col  = (int*)alloc((size_t)NN * STRIDE * 4);     // padded CSR (28.8 MB)
    int*   ofl  = (int*)alloc((size_t)4096 * 2 * 4);        // overflow pairs

    int* ofc = deg + NN;

    hipMemsetAsync(deg, 0, (size_t)(NN + 64) * 4, stream);

    // padded CSR build || layer-0 GEMM || out init, one grid
    k_build<<<NB_EDGE + NB_GEMM + NB_OUT, 256, 0, stream>>>(
        ei, deg, col, ofc, ofl,
        x, Wm[0], As[0], Ad[0], H, als, ald, hb, out);

    k_aggf<<<NN / 16, 256, 0, stream>>>(H,  als,  ald,  deg, col, ofc, ofl, Bb[0],
                                        Wm[1], As[1], Ad[1], Bf, als2, ald2);
    k_aggf<<<NN / 16, 256, 0, stream>>>(Bf, als2, ald2, deg, col, ofc, ofl, Bb[1],
                                        Wm[2], As[2], Ad[2], H, als, ald);
    k_aggl<<<NN / 16, 256, 0, stream>>>(H,  als,  ald,  deg, col, ofc, ofl, Bb[2],
                                        batch, hw, out);
}